// Round 8
// baseline (288.310 us; speedup 1.0000x reference)
//
#include <hip/hip_runtime.h>
#include <hip/hip_bf16.h>

// SDPA with materialized attention. Contiguous-footprint redesign.
// B=16, LQ=LK=2048, D=64. d_out = out [B,LQ,D] f32 then attn [B,LQ,LK] f32.
// K1 (block = 16 consecutive q-rows x full k):
//   e = !mask * exp2(QK^T/8*log2e) -> ws bf16 (block-contiguous 64KB),
//   full rowsums -> out[row][0], then attn rows = e*rinv (16 x 8KB sequential).
// K2: PV on raw e (L3-hot) + out = acc * rinv (overwrites rowsum stash).
namespace {
constexpr int kB = 16;
constexpr int kLQ = 2048;
constexpr int kLK = 2048;
constexpr int kD = 64;
constexpr float kLog2e = 1.44269504088896340736f;
constexpr int kKStrB = 144;   // K-stage LDS row: 64 bf16 = 128B + 16 pad
constexpr int kMStrB = 136;   // mask-stage LDS row: 128B + 8 pad
constexpr int kBStrB = 272;   // e-bounce LDS row: 128 bf16 = 256B + 16 pad
constexpr int kChunk = 256;   // K2 column chunk
constexpr int kEStrB = 528;   // K2 e-chunk LDS row: 256 bf16 = 512B + 16 pad
}

using short8 = __attribute__((ext_vector_type(8))) short;
using f32x4  = __attribute__((ext_vector_type(4))) float;

union S8U { short8 v; unsigned u[4]; };

static __device__ __forceinline__ unsigned pk2(float lo, float hi) {
    __hip_bfloat162 h = __float22bfloat162_rn(float2{lo, hi});
    unsigned short a = __builtin_bit_cast(unsigned short, h.x);
    unsigned short b = __builtin_bit_cast(unsigned short, h.y);
    return (unsigned)a | ((unsigned)b << 16);
}
static __device__ __forceinline__ float bf2f(unsigned short s) {
    unsigned u = ((unsigned)s) << 16;
    return __builtin_bit_cast(float, u);
}

// ---------------- K1: QK^T + mask + exp2 + rowsum + attn rows ----------------
__global__ __launch_bounds__(256, 6) void k1_fused(
    const float* __restrict__ qg, const float* __restrict__ kg,
    const void* __restrict__ maskg, unsigned short* __restrict__ ews,
    float* __restrict__ attng, float* __restrict__ outg)
{
    __shared__ __align__(16) unsigned char s_kst[128 * kKStrB];  // K sub bf16 [128][64]
    __shared__ __align__(16) unsigned char s_mst[16 * kMStrB];   // mask flags [16][128]
    __shared__ __align__(16) unsigned char s_bnc[16 * kBStrB];   // e bounce [16][128] bf16
    __shared__ float s_wsum[4][16];
    __shared__ float s_rinv[16];
    __shared__ int s_flag;

    const int tid = threadIdx.x;
    const int wave = tid >> 6;          // 0..3: owns cols wave*32 of each 128-sub
    const int lane = tid & 63;
    const int r16 = lane & 15;
    const int g = lane >> 4;

    const int blk = blockIdx.x;
    const int b = blk >> 7;
    const int qt = blk & 127;
    const size_t grow0 = (size_t)b * kLQ + qt * 16;   // first global q-row

    // mask dtype detection: int32 0/1 words have bytes 1..3 == 0
    if (tid < 64) {
        unsigned w = ((const unsigned*)maskg)[tid];
        unsigned long long bal = __ballot((w & 0xFFFFFF00u) != 0u);
        if (tid == 0) s_flag = (bal != 0ull) ? 1 : 0;
    }
    __syncthreads();
    const bool mask_byte = (s_flag != 0);
    const unsigned char* mask_u8 = (const unsigned char*)maskg;
    const int* mask_i32 = (const int*)maskg;

    // Q fragment (shared rows for all 4 waves), scale folded (0.125*log2e)
    short8 q0, q1;
    {
        const float4* qp = (const float4*)(qg + (grow0 + r16) * kD);
        const float s = 0.125f * kLog2e;
        float4 x0 = qp[2*g + 0], x1 = qp[2*g + 1];
        float4 x2 = qp[2*g + 8], x3 = qp[2*g + 9];
        x0 *= s; x1 *= s; x2 *= s; x3 *= s;
        S8U a, c;
        a.u[0] = pk2(x0.x, x0.y); a.u[1] = pk2(x0.z, x0.w);
        a.u[2] = pk2(x1.x, x1.y); a.u[3] = pk2(x1.z, x1.w);
        c.u[0] = pk2(x2.x, x2.y); c.u[1] = pk2(x2.z, x2.w);
        c.u[2] = pk2(x3.x, x3.y); c.u[3] = pk2(x3.z, x3.w);
        q0 = a.v; q1 = c.v;
    }

    float wsum = 0.f;

    for (int sub = 0; sub < kLK / 128; ++sub) {
        const int csub = sub * 128;
        // ---- K stage: 128 k-rows x 64 d, fully coalesced (4 rows x 256B per instr) ----
#pragma unroll
        for (int i = 0; i < 8; ++i) {
            const int row = (tid >> 4) + i * 16;
            const float4 y = *(const float4*)(kg + ((size_t)b * kLK + csub + row) * kD + (tid & 15) * 4);
            uint2 p{ pk2(y.x, y.y), pk2(y.z, y.w) };
            *(uint2*)(s_kst + row * kKStrB + (tid & 15) * 8) = p;
        }
        // ---- mask stage: 16 rows x 128 cols -> byte flags ----
        {
            const int mrow = tid >> 4;
            const int mseg = tid & 15;
            unsigned long long f;
            if (mask_byte) {
                f = *(const unsigned long long*)(mask_u8 + (grow0 + mrow) * kLK + csub + mseg * 8);
            } else {
                const int* mp = mask_i32 + (grow0 + mrow) * kLK + csub + mseg * 8;
                const int4 m0 = *(const int4*)mp;
                const int4 m1 = *(const int4*)(mp + 4);
                f  = (m0.x ? 1ull : 0ull)        | (m0.y ? 1ull << 8 : 0ull)
                   | (m0.z ? 1ull << 16 : 0ull)  | (m0.w ? 1ull << 24 : 0ull)
                   | (m1.x ? 1ull << 32 : 0ull)  | (m1.y ? 1ull << 40 : 0ull)
                   | (m1.z ? 1ull << 48 : 0ull)  | (m1.w ? 1ull << 56 : 0ull);
            }
            *(unsigned long long*)(s_mst + mrow * kMStrB + mseg * 8) = f;
        }
        __syncthreads();

        // ---- fragments from LDS, MFMA (swapped operands), mask, exp2 ----
        const unsigned char* kb = s_kst + (wave * 32 + r16) * kKStrB;
        const short8 kA0 = *(const short8*)(kb + g * 16);
        const short8 kA1 = *(const short8*)(kb + 64 + g * 16);
        const short8 kB0 = *(const short8*)(kb + 16 * kKStrB + g * 16);
        const short8 kB1 = *(const short8*)(kb + 16 * kKStrB + 64 + g * 16);
        f32x4 accA = {0.f, 0.f, 0.f, 0.f}, accB = {0.f, 0.f, 0.f, 0.f};
        accA = __builtin_amdgcn_mfma_f32_16x16x32_bf16(kA0, q0, accA, 0, 0, 0);
        accA = __builtin_amdgcn_mfma_f32_16x16x32_bf16(kA1, q1, accA, 0, 0, 0);
        accB = __builtin_amdgcn_mfma_f32_16x16x32_bf16(kB0, q0, accB, 0, 0, 0);
        accB = __builtin_amdgcn_mfma_f32_16x16x32_bf16(kB1, q1, accB, 0, 0, 0);

        // lane reg r: S[q=r16][col = csub + wave*32 (+16) + 4g + r]
        const unsigned mwA = *(const unsigned*)(s_mst + r16 * kMStrB + wave * 32 + 4 * g);
        const unsigned mwB = *(const unsigned*)(s_mst + r16 * kMStrB + wave * 32 + 16 + 4 * g);
        float eA[4], eB[4];
#pragma unroll
        for (int r = 0; r < 4; ++r) {
            eA[r] = ((mwA >> (8*r)) & 0xFFu) ? 0.f : __builtin_amdgcn_exp2f(accA[r]);
            eB[r] = ((mwB >> (8*r)) & 0xFFu) ? 0.f : __builtin_amdgcn_exp2f(accB[r]);
        }
        wsum += (eA[0] + eA[1]) + (eA[2] + eA[3]) + (eB[0] + eB[1]) + (eB[2] + eB[3]);
        uint2 pA{ pk2(eA[0], eA[1]), pk2(eA[2], eA[3]) };
        uint2 pB{ pk2(eB[0], eB[1]), pk2(eB[2], eB[3]) };
        *(uint2*)(s_bnc + r16 * kBStrB + wave * 64 + 8 * g) = pA;
        *(uint2*)(s_bnc + r16 * kBStrB + wave * 64 + 32 + 8 * g) = pB;
        __syncthreads();

        // ---- e store: 16 rows x 256B, block footprint contiguous in ws ----
        {
            const int erow = tid >> 4;
            const int eseg = tid & 15;
            *(short8*)(ews + (grow0 + erow) * kLK + csub + eseg * 8) =
                *(const short8*)(s_bnc + erow * kBStrB + eseg * 16);
        }
    }

    // ---- full rowsums -> rinv + stash for K2 ----
    wsum += __shfl_xor(wsum, 16, 64);
    wsum += __shfl_xor(wsum, 32, 64);
    if (g == 0) s_wsum[wave][r16] = wsum;
    __syncthreads();
    if (tid < 16) {
        const float rs = s_wsum[0][tid] + s_wsum[1][tid] + s_wsum[2][tid] + s_wsum[3][tid];
        outg[(grow0 + tid) * kD] = rs;                 // rowsum stash for K2
        s_rinv[tid] = __builtin_amdgcn_rcpf(rs);
    }
    __syncthreads();

    // ---- attn rows: 16 x 8KB fully sequential writes (e re-read is L2-hot) ----
#pragma unroll 2
    for (int r = 0; r < 16; ++r) {
        const float rinv = s_rinv[r];
        const short8 ev = *(const short8*)(ews + (grow0 + r) * kLK + tid * 8);
        f32x4 a0, a1;
        a0[0] = bf2f((unsigned short)ev[0]) * rinv;
        a0[1] = bf2f((unsigned short)ev[1]) * rinv;
        a0[2] = bf2f((unsigned short)ev[2]) * rinv;
        a0[3] = bf2f((unsigned short)ev[3]) * rinv;
        a1[0] = bf2f((unsigned short)ev[4]) * rinv;
        a1[1] = bf2f((unsigned short)ev[5]) * rinv;
        a1[2] = bf2f((unsigned short)ev[6]) * rinv;
        a1[3] = bf2f((unsigned short)ev[7]) * rinv;
        float* ap = attng + (grow0 + r) * kLK + tid * 8;
        *(f32x4*)ap = a0;
        *(f32x4*)(ap + 4) = a1;
    }
}

// ---------------- K2: PV on raw e + out scale ----------------
__global__ __launch_bounds__(512, 8) void k2_pv(
    const float* __restrict__ vg, const unsigned short* __restrict__ ews,
    float* __restrict__ outg)
{
    __shared__ __align__(16) unsigned char s_e[16 * kEStrB];  // raw e bf16 [16][256]
    __shared__ float s_red[16][kD];
    __shared__ float s_rinv[16];

    const int tid = threadIdx.x;
    const int wave = tid >> 6;
    const int lane = tid & 63;
    const int r16 = lane & 15;
    const int g = lane >> 4;

    const int blk = blockIdx.x;
    const int b = blk >> 7;
    const size_t grow0 = (size_t)b * kLQ + (blk & 127) * 16;

    if (tid < 16)
        s_rinv[tid] = __builtin_amdgcn_rcpf(outg[(grow0 + tid) * kD]);
    __syncthreads();

    const int d0 = (wave & 3) * 16;
    const int kh = wave >> 2;
    f32x4 acc = {0.f, 0.f, 0.f, 0.f};
    const float* vbase = vg + (size_t)b * kLK * kD + d0 + r16;

    for (int chunk = 0; chunk < kLK / kChunk; ++chunk) {
        const int c0 = chunk * kChunk;
        {
            const int row = tid >> 5;
            const int cc = tid & 31;
            const short8 ev = *(const short8*)(ews + (grow0 + row) * kLK + c0 + cc * 8);
            *(short8*)(s_e + row * kEStrB + cc * 16) = ev;
        }
        __syncthreads();
#pragma unroll
        for (int s = 0; s < 4; ++s) {
            const int kk = kh * 128 + s * 32 + 8 * g;
            const short8 af = *(const short8*)(s_e + r16 * kEStrB + kk * 2);
            const float* vp = vbase + (size_t)(c0 + kk) * kD;
            float v0 = vp[0*kD], v1 = vp[1*kD], v2 = vp[2*kD], v3 = vp[3*kD];
            float v4 = vp[4*kD], v5 = vp[5*kD], v6 = vp[6*kD], v7 = vp[7*kD];
            S8U bv;
            bv.u[0] = pk2(v0, v1); bv.u[1] = pk2(v2, v3);
            bv.u[2] = pk2(v4, v5); bv.u[3] = pk2(v6, v7);
            acc = __builtin_amdgcn_mfma_f32_16x16x32_bf16(af, bv.v, acc, 0, 0, 0);
        }
        __syncthreads();
    }

    if (kh == 1) {
#pragma unroll
        for (int r = 0; r < 4; ++r) s_red[4*g + r][d0 + r16] = acc[r];
    }
    __syncthreads();
    if (kh == 0) {
#pragma unroll
        for (int r = 0; r < 4; ++r) {
            const int m = 4*g + r;
            outg[(grow0 + m) * kD + d0 + r16] = (acc[r] + s_red[m][d0 + r16]) * s_rinv[m];
        }
    }
}

extern "C" void kernel_launch(void* const* d_in, const int* in_sizes, int n_in,
                              void* d_out, int out_size, void* d_ws, size_t ws_size,
                              hipStream_t stream) {
    (void)in_sizes; (void)n_in; (void)out_size; (void)ws_size;
    const float* q = (const float*)d_in[0];
    const float* k = (const float*)d_in[1];
    const float* v = (const float*)d_in[2];
    const void* mask = d_in[3];
    float* out = (float*)d_out;
    float* attn = out + (size_t)kB * kLQ * kD;
    unsigned short* ews = (unsigned short*)d_ws;   // 134 MB bf16 e
    k1_fused<<<dim3(kB * 128), 256, 0, stream>>>(q, k, mask, ews, attn, out);
    k2_pv<<<dim3(kB * 128), 512, 0, stream>>>(v, ews, out);
}